// Round 14
// baseline (82.321 us; speedup 1.0000x reference)
//
#include <hip/hip_runtime.h>

// images=8, patches=3600(=60*60), hor_f=64, ver_f=25(=5*5), 64x64 px, k=5
#define OH     60
#define NIMG   8
#define HF     64
#define VF     25
#define NPATCH 3600
#define CDIM   1600                  // HF*VF

typedef float floatx4 __attribute__((ext_vector_type(4)));  // native vec for nt-store

// ---- fold v2: grid (hg 16, strip 12, im 8) = 1536 blocks, 256 threads ----
// FH=4 -> LDS 25.6 KB -> 6 blocks/CU (vs 3): finer barrier domains, better
// latency hiding. Same per-thread ratios as r8 fold (6 f4 stage, 125 LDS+add).
#define FH   4                       // h channels per block
#define FC   (FH * VF)               // 100 c values
#define SPI  5                       // pi rows per strip
#define PJS  64                      // pj stride (XOR-swizzled)
#define NSTRIP 12
#define SROWS  9                     // SPI + 4 halo rows
#define NF4R 1500                    // f4 per staged row: 60 patches * 25 f4

__global__ __launch_bounds__(256, 6) void fold_kernel(const float* __restrict__ x,
                                                      float* __restrict__ slab) {
    __shared__ float lb[FC * PJS];   // 100*64 fl = 25.6 KB
    const int hg = blockIdx.x, strip = blockIdx.y, im = blockIdx.z;
    const int t = threadIdx.x;
    const int h0 = hg * FH;
    const int pi0 = strip * SPI;
    const int j = t & 63, g = t >> 6;          // g = local h (0..3)

    float acc[SROWS];
#pragma unroll
    for (int k = 0; k < SROWS; ++k) acc[k] = 0.f;

    const float* xb = x + ((size_t)im * NPATCH + (size_t)pi0 * OH) * CDIM + h0 * VF;

    // row-invariant staging offsets (u = t + 256k, active if u < 1500)
    int off_g[6], off_l[6];
#pragma unroll
    for (int k = 0; k < 6; ++k) {
        int u = t + 256 * k;
        if (u < NF4R) {
            int pj = u / 25, c4 = u - 25 * pj;
            off_g[k] = pj * CDIM + (c4 << 2);
            off_l[k] = (c4 << 8) + (pj ^ (c4 & 31));   // <=2-way write alias: free
        }
    }

    float4 stg[6];
#pragma unroll
    for (int k = 0; k < 6; ++k)
        if (t + 256 * k < NF4R)
            stg[k] = *reinterpret_cast<const float4*>(xb + off_g[k]);

#pragma unroll
    for (int row = 0; row < SPI; ++row) {
        if (row) __syncthreads();
#pragma unroll
        for (int k = 0; k < 6; ++k)
            if (t + 256 * k < NF4R) {
                float4 v = stg[k];
                int a = off_l[k];
                lb[a]           = v.x;
                lb[a + PJS]     = v.y;
                lb[a + 2 * PJS] = v.z;
                lb[a + 3 * PJS] = v.w;
            }
        if (row + 1 < SPI) {                   // prefetch next row during compute
#pragma unroll
            for (int k = 0; k < 6; ++k)
                if (t + 256 * k < NF4R)
                    stg[k] = *reinterpret_cast<const float4*>(
                        xb + (size_t)(row + 1) * OH * CDIM + off_g[k]);
        }
        __syncthreads();
        // compute: lane j, h=g fixed; reads lane-consecutive ^ const -> conflict-free
#pragma unroll
        for (int di = 0; di < 5; ++di) {
#pragma unroll
            for (int dj = 0; dj < 5; ++dj) {
                int c = g * VF + di * 5 + dj;
                int pjr = j - dj;
                if ((unsigned)pjr < 60u)
                    acc[row + di] += lb[c * PJS + (pjr ^ ((c >> 2) & 31))];
            }
        }
    }

    // epilogue: 9 plain coalesced stores (256B/wave), disjoint slab region
    float* sb = slab + (((size_t)(strip * 8 + im) * 64 + h0 + g) * SROWS) * 64 + j;
#pragma unroll
    for (int il = 0; il < SROWS; ++il) sb[il * 64] = acc[il];
}

// ---- unfold (r13, unchanged): grid (hh 4, pi 60, im 8), 256 thr, NT stores ----
#define UH   16                      // channels per block
#define LJS  68                      // padded j stride (f4-aligned)

__global__ __launch_bounds__(256) void unfold_kernel(const float* __restrict__ slab,
                                                     float* __restrict__ out) {
    __shared__ float li[UH * 5 * LJS];         // 5440 fl = 21.76 KB
    __shared__ int4 lut[100];
    const int hh = blockIdx.x;                 // 0..3
    const int pi = blockIdx.y;                 // 0..59
    const int im = blockIdx.z;
    const int t = threadIdx.x;
    const int h0 = hh * UH;

    if (t < 100) {                             // f4-slot r -> 4 LDS offsets (R*LJS+dj)
        int4 e;
        int* ep = &e.x;
#pragma unroll
        for (int k = 0; k < 4; ++k) {
            int fl = 4 * t + k;                // = ho*25 + v
            int ho = fl / 25, v = fl - 25 * ho;
            int di = v / 5, dj = v - 5 * di;
            ep[k] = (ho * 5 + di) * LJS + dj;
        }
        lut[t] = e;
    }

    // stage rows pi..pi+4 of 16 channels (strip-summed), pre-scaled by 1/(ci*cj)
    for (int u = t; u < UH * 5 * 16; u += 256) {
        int ch = u / 80, rem = u - 80 * ch;
        int di = rem >> 4, j4 = rem & 15;
        int i = pi + di;
        int s_hi = min(i / 5, NSTRIP - 1);
        int s_lo = (i <= 8) ? 0 : (i - 4) / 5;
        const float* pa = slab +
            (((size_t)(s_lo * 8 + im) * 64 + h0 + ch) * SROWS + (i - 5 * s_lo)) * 64 + (j4 << 2);
        float4 v = *reinterpret_cast<const float4*>(pa);
        if (s_hi != s_lo) {
            const float* pb = slab +
                (((size_t)(s_hi * 8 + im) * 64 + h0 + ch) * SROWS + (i - 5 * s_hi)) * 64 + (j4 << 2);
            float4 w = *reinterpret_cast<const float4*>(pb);
            v.x += w.x; v.y += w.y; v.z += w.z; v.w += w.w;
        }
        float ri = 1.0f / (float)min(min(i + 1, 64 - i), 5);
        int jb = j4 << 2;
        float4 w;
        w.x = v.x * ri * (1.0f / (float)min(min(jb + 1, 64 - jb), 5));
        w.y = v.y * ri * (1.0f / (float)min(min(jb + 2, 63 - jb), 5));
        w.z = v.z * ri * (1.0f / (float)min(min(jb + 3, 62 - jb), 5));
        w.w = v.w * ri * (1.0f / (float)min(min(jb + 4, 61 - jb), 5));
        *reinterpret_cast<float4*>(&li[(ch * 5 + di) * LJS + jb]) = w;
    }
    __syncthreads();

    // emit: 60 pj x 100 float4, LUT-addressed, NON-TEMPORAL coalesced writes.
    // nt keeps out (never re-read) from evicting x+slab in L3 across replays.
    float* ob = out + ((size_t)im * NPATCH + (size_t)pi * OH) * CDIM + h0 * VF;
    for (int u = t; u < 6000; u += 256) {
        int pj = u / 100, r = u - 100 * pj;
        int4 e = lut[r];
        floatx4 o;
        o.x = li[e.x + pj];
        o.y = li[e.y + pj];
        o.z = li[e.z + pj];
        o.w = li[e.w + pj];
        __builtin_nontemporal_store(o,
            reinterpret_cast<floatx4*>(ob + (size_t)pj * CDIM + 4 * r));
    }
}

extern "C" void kernel_launch(void* const* d_in, const int* in_sizes, int n_in,
                              void* d_out, int out_size, void* d_ws, size_t ws_size,
                              hipStream_t stream) {
    const float* x = (const float*)d_in[0];
    float* slab = (float*)d_ws;                // 12*8*64*9*64 fl = 14.2 MB
    float* out  = (float*)d_out;

    fold_kernel<<<dim3(16, NSTRIP, NIMG), 256, 0, stream>>>(x, slab);  // 1536 blocks
    unfold_kernel<<<dim3(4, OH, NIMG), 256, 0, stream>>>(slab, out);   // 1920 blocks

    (void)out_size; (void)ws_size; (void)in_sizes; (void)n_in;
}

// Round 15
// 76.226 us; speedup vs baseline: 1.0800x; 1.0800x over previous
//
#include <hip/hip_runtime.h>

// images=8, patches=3600(=60*60), hor_f=64, ver_f=25(=5*5), 64x64 px, k=5
#define OH     60
#define NIMG   8
#define HF     64
#define VF     25
#define NPATCH 3600
#define CDIM   1600                  // HF*VF

typedef float floatx4 __attribute__((ext_vector_type(4)));  // native vec for nt-store

// ---- fold (r13 structure): 1D grid 768, XCD-pinned: im = b & 7 ----
// 768 = 96 * 8 -> every XCD gets exactly the 96 blocks of one image;
// per-image slab slice (1.77 MB) then lives in that XCD's 4 MB L2.
#define FH   8                       // h channels per block
#define FC   (FH * VF)               // 200 c values
#define SPI  5                       // pi rows per strip
#define PJS  64                      // pj stride (XOR-swizzled)
#define NSTRIP 12
#define SROWS  9                     // SPI + 4 halo rows

__global__ __launch_bounds__(512, 6) void fold_kernel(const float* __restrict__ x,
                                                      float* __restrict__ slab) {
    __shared__ float lb[FC * PJS];   // 51.2 KB
    const int b = blockIdx.x;
    const int im = b & 7;            // XCD pin (blockIdx round-robins mod 8)
    const int rem = b >> 3;          // 0..95
    const int hg = rem & 7, strip = rem >> 3;
    const int t = threadIdx.x;
    const int h0 = hg * FH;
    const int pi0 = strip * SPI;
    const int j = t & 63, g = t >> 6;          // g = local h (0..7)

    float acc[SROWS];
#pragma unroll
    for (int k = 0; k < SROWS; ++k) acc[k] = 0.f;

    const float* xb = x + ((size_t)im * NPATCH + (size_t)pi0 * OH) * CDIM + h0 * VF;

    int off_g[6], off_l[6];
#pragma unroll
    for (int k = 0; k < 6; ++k) {
        int u = t + 512 * k;
        if (u < 3000) {
            int pj = u / 50, c4 = u - 50 * pj;
            off_g[k] = pj * CDIM + (c4 << 2);
            off_l[k] = (c4 << 8) + (pj ^ (c4 & 31));
        }
    }

    float4 stg[6];
#pragma unroll
    for (int k = 0; k < 6; ++k)
        if (t + 512 * k < 3000)
            stg[k] = *reinterpret_cast<const float4*>(xb + off_g[k]);

#pragma unroll
    for (int row = 0; row < SPI; ++row) {
        if (row) __syncthreads();
#pragma unroll
        for (int k = 0; k < 6; ++k)
            if (t + 512 * k < 3000) {
                float4 v = stg[k];
                int a = off_l[k];
                lb[a]           = v.x;
                lb[a + PJS]     = v.y;
                lb[a + 2 * PJS] = v.z;
                lb[a + 3 * PJS] = v.w;
            }
        if (row + 1 < SPI) {                   // prefetch next row during compute
#pragma unroll
            for (int k = 0; k < 6; ++k)
                if (t + 512 * k < 3000)
                    stg[k] = *reinterpret_cast<const float4*>(
                        xb + (size_t)(row + 1) * OH * CDIM + off_g[k]);
        }
        __syncthreads();
#pragma unroll
        for (int di = 0; di < 5; ++di) {
#pragma unroll
            for (int dj = 0; dj < 5; ++dj) {
                int c = g * VF + di * 5 + dj;
                int pjr = j - dj;
                if ((unsigned)pjr < 60u)
                    acc[row + di] += lb[c * PJS + (pjr ^ ((c >> 2) & 31))];
            }
        }
    }

    float* sb = slab + (((size_t)(strip * 8 + im) * 64 + h0 + g) * SROWS) * 64 + j;
#pragma unroll
    for (int il = 0; il < SROWS; ++il) sb[il * 64] = acc[il];
}

// ---- unfold (r13 structure): 1D grid 1920, XCD-pinned: im = b & 7 ----
// 1920 = 240 * 8 -> reader blocks of image im land on the XCD holding its slab.
#define UH   16                      // channels per block
#define LJS  68                      // padded j stride (f4-aligned)

__global__ __launch_bounds__(256) void unfold_kernel(const float* __restrict__ slab,
                                                     float* __restrict__ out) {
    __shared__ float li[UH * 5 * LJS];         // 5440 fl = 21.76 KB
    __shared__ int4 lut[100];
    const int b = blockIdx.x;
    const int im = b & 7;            // XCD pin
    const int rem = b >> 3;          // 0..239
    const int hh = rem & 3, pi = rem >> 2;     // hh 0..3, pi 0..59
    const int t = threadIdx.x;
    const int h0 = hh * UH;

    if (t < 100) {                             // f4-slot r -> 4 LDS offsets (R*LJS+dj)
        int4 e;
        int* ep = &e.x;
#pragma unroll
        for (int k = 0; k < 4; ++k) {
            int fl = 4 * t + k;                // = ho*25 + v
            int ho = fl / 25, v = fl - 25 * ho;
            int di = v / 5, dj = v - 5 * di;
            ep[k] = (ho * 5 + di) * LJS + dj;
        }
        lut[t] = e;
    }

    // stage rows pi..pi+4 of 16 channels (strip-summed), pre-scaled by 1/(ci*cj)
    for (int u = t; u < UH * 5 * 16; u += 256) {
        int ch = u / 80, rem2 = u - 80 * ch;
        int di = rem2 >> 4, j4 = rem2 & 15;
        int i = pi + di;
        int s_hi = min(i / 5, NSTRIP - 1);
        int s_lo = (i <= 8) ? 0 : (i - 4) / 5;
        const float* pa = slab +
            (((size_t)(s_lo * 8 + im) * 64 + h0 + ch) * SROWS + (i - 5 * s_lo)) * 64 + (j4 << 2);
        float4 v = *reinterpret_cast<const float4*>(pa);
        if (s_hi != s_lo) {
            const float* pb = slab +
                (((size_t)(s_hi * 8 + im) * 64 + h0 + ch) * SROWS + (i - 5 * s_hi)) * 64 + (j4 << 2);
            float4 w = *reinterpret_cast<const float4*>(pb);
            v.x += w.x; v.y += w.y; v.z += w.z; v.w += w.w;
        }
        float ri = 1.0f / (float)min(min(i + 1, 64 - i), 5);
        int jb = j4 << 2;
        float4 w;
        w.x = v.x * ri * (1.0f / (float)min(min(jb + 1, 64 - jb), 5));
        w.y = v.y * ri * (1.0f / (float)min(min(jb + 2, 63 - jb), 5));
        w.z = v.z * ri * (1.0f / (float)min(min(jb + 3, 62 - jb), 5));
        w.w = v.w * ri * (1.0f / (float)min(min(jb + 4, 61 - jb), 5));
        *reinterpret_cast<float4*>(&li[(ch * 5 + di) * LJS + jb]) = w;
    }
    __syncthreads();

    // emit: 60 pj x 100 float4, LUT-addressed, NON-TEMPORAL coalesced writes.
    // nt keeps out (never re-read) from evicting x+slab in L3 across replays.
    float* ob = out + ((size_t)im * NPATCH + (size_t)pi * OH) * CDIM + h0 * VF;
    for (int u = t; u < 6000; u += 256) {
        int pj = u / 100, r = u - 100 * pj;
        int4 e = lut[r];
        floatx4 o;
        o.x = li[e.x + pj];
        o.y = li[e.y + pj];
        o.z = li[e.z + pj];
        o.w = li[e.w + pj];
        __builtin_nontemporal_store(o,
            reinterpret_cast<floatx4*>(ob + (size_t)pj * CDIM + 4 * r));
    }
}

extern "C" void kernel_launch(void* const* d_in, const int* in_sizes, int n_in,
                              void* d_out, int out_size, void* d_ws, size_t ws_size,
                              hipStream_t stream) {
    const float* x = (const float*)d_in[0];
    float* slab = (float*)d_ws;                // 12*8*64*9*64 fl = 14.2 MB
    float* out  = (float*)d_out;

    fold_kernel<<<768, 512, 0, stream>>>(x, slab);      // 96 blocks per image/XCD
    unfold_kernel<<<1920, 256, 0, stream>>>(slab, out); // 240 blocks per image/XCD

    (void)out_size; (void)ws_size; (void)in_sizes; (void)n_in;
}